// Round 5
// baseline (141.140 us; speedup 1.0000x reference)
//
#include <hip/hip_runtime.h>
#include <hip/hip_bf16.h>
#include <stdint.h>

#define HWN 50176   // 224*224
#define NM  1000
#define FD  128
#define NSPLIT 98   // 512-wide k-chunks
#define KSTEPS 16
#define NSCAN 20
#define NPB 50      // 1000 / 20

typedef __attribute__((ext_vector_type(8))) short short8;
typedef __attribute__((ext_vector_type(4))) float f32x4;

__device__ __forceinline__ unsigned short f2bf(float x) {
    union { float f; unsigned u; } v; v.f = x;
    unsigned r = v.u + 0x7FFFu + ((v.u >> 16) & 1u);
    return (unsigned short)(r >> 16);
}

#define AS1(p) ((const __attribute__((address_space(1))) unsigned int*)(p))
#define AS3(p) ((__attribute__((address_space(3))) unsigned int*)(p))

// Stage 1: A[hw,f] = sum_c img*W, packed bf16 k-tiles (B operand of the GEMM).
// Tile kt (8192B): 16B slot s = c*128 + ((f+c)&127) holds chunk c of feature f.
__global__ __launch_bounds__(256) void k_encode(const float* __restrict__ img,
                                                const float* __restrict__ Wt,
                                                unsigned short* __restrict__ Bpack,
                                                float* __restrict__ rep0part)
{
    const int t = threadIdx.x;
    const int f = t & 127;
    const int kt = blockIdx.x * 2 + (t >> 7);
    const int hw0 = kt * 32;
    float vals[32];
    float rsum = 0.f;
#pragma unroll
    for (int e = 0; e < 32; ++e) {
        const int hw = hw0 + e;
        float a = img[hw] * Wt[(size_t)hw * FD + f];
        a = fmaf(img[HWN + hw],     Wt[(size_t)(HWN + hw) * FD + f], a);
        a = fmaf(img[2 * HWN + hw], Wt[(size_t)(2 * HWN + hw) * FD + f], a);
        vals[e] = a;
        rsum += a;
    }
    char* tile = (char*)Bpack + (size_t)kt * 8192;
#pragma unroll
    for (int j = 0; j < 4; ++j) {
        short8 pk;
#pragma unroll
        for (int e = 0; e < 8; ++e) pk[e] = (short)f2bf(vals[j * 8 + e]);
        *reinterpret_cast<short8*>(tile + j * 2048 + (((f + j) & 127) << 4)) = pk;
    }
    __shared__ float red[256];
    red[t] = rsum;
    __syncthreads();
    if (t < 128) rep0part[(size_t)blockIdx.x * 128 + f] = red[t] + red[t + 128];
}

// Stage 2: rep0[f] = sum of 784 partials
__global__ __launch_bounds__(256) void k_rep0red(const float* __restrict__ rep0part,
                                                 float* __restrict__ rep0)
{
    const int f = blockIdx.x;
    float s = 0.f;
    for (int b = threadIdx.x; b < 784; b += 256) s += rep0part[(size_t)b * 128 + f];
    __shared__ float red[256];
    red[threadIdx.x] = s;
    __syncthreads();
    for (int o = 128; o > 0; o >>= 1) {
        if (threadIdx.x < o) red[threadIdx.x] += red[threadIdx.x + o];
        __syncthreads();
    }
    if (threadIdx.x == 0) rep0[f] = red[0];
}

// Stage 3: split-K GEMM. 128-row M-tile, 8 waves/512 thr, grid 8x98.
// Counted-vmcnt 3-buffer pipeline (stage ks+2 while computing ks; wait
// vmcnt(3) steady state). All k-loop vmem via global_load_lds (3 ops/thread)
// so the manual counts are exact.
__global__ __launch_bounds__(512, 4) void k_gemm(const float* __restrict__ masks,
                                                 const unsigned short* __restrict__ Bpack,
                                                 float* __restrict__ partial)
{
    __shared__ __align__(16) char lds[3][24576];   // A fp32 16KB | B bf16 8KB

    const int t = threadIdx.x;
    const int wv = t >> 6, lane = t & 63;
    const int lrow = lane & 15, kg = lane >> 4;
    const int mtile = blockIdx.x, split = blockIdx.y;
    const int n0 = mtile * 128;

    // ---- A staging: 128 rows x 32 k fp32 = 16KB, 2 gll ops/thread.
    // Linear LDS slot s (16B units): row = s>>3, holds source chunk
    // c = (s&7) ^ (row&7) (inverse-swizzled source, linear dest).
    const int r0s = t >> 3, r1s = 64 + (t >> 3);
    const int c0 = (t & 7) ^ (r0s & 7);           // (r1s&7)==(r0s&7)
    int arow0 = n0 + r0s; if (arow0 >= NM) arow0 = NM - 1;  // dup rows never read back
    int arow1 = n0 + r1s; if (arow1 >= NM) arow1 = NM - 1;
    const float* aSrc0 = masks + (size_t)arow0 * HWN + split * 512 + c0 * 4;
    const float* aSrc1 = masks + (size_t)arow1 * HWN + split * 512 + c0 * 4;
    const char*  bSrc  = (const char*)Bpack + (size_t)split * (KSTEPS * 8192) + t * 16;

    // ---- fragment read offsets (loop-invariant)
    const int r = wv * 16 + lrow;
    const int ao0 = r * 128 + (((2 * kg)     ^ (r & 7)) << 4);
    const int ao1 = r * 128 + ((((2 * kg)+1) ^ (r & 7)) << 4);
    int bo[8];
#pragma unroll
    for (int ft = 0; ft < 8; ++ft)
        bo[ft] = 16384 + kg * 2048 + (((ft * 16 + lrow + kg) & 127) << 4);

    f32x4 acc[8];
#pragma unroll
    for (int i = 0; i < 8; ++i) acc[i] = f32x4{0.f, 0.f, 0.f, 0.f};

#define STAGE(KS, BUF) do {                                                                              \
        char* b_ = &lds[BUF][0];                                                                         \
        __builtin_amdgcn_global_load_lds(AS1(aSrc0 + (KS) * 32), AS3(b_ + t * 16), 16, 0, 0);            \
        __builtin_amdgcn_global_load_lds(AS1(aSrc1 + (KS) * 32), AS3(b_ + 8192 + t * 16), 16, 0, 0);     \
        __builtin_amdgcn_global_load_lds(AS1(bSrc + (size_t)(KS) * 8192), AS3(b_ + 16384 + t * 16), 16, 0, 0); \
    } while (0)

    STAGE(0, 0);
    STAGE(1, 1);
    asm volatile("s_waitcnt vmcnt(3)" ::: "memory");   // step0 landed; step1 in flight
    __builtin_amdgcn_s_barrier();
    __builtin_amdgcn_sched_barrier(0);

    int cur = 0, stg = 2;
    for (int ks = 0; ks < KSTEPS; ++ks) {
        if (ks + 2 < KSTEPS) STAGE(ks + 2, stg);

        const char* A = &lds[cur][0];
        const f32x4 alo = *reinterpret_cast<const f32x4*>(A + ao0);
        const f32x4 ahi = *reinterpret_cast<const f32x4*>(A + ao1);
        union { short8 s; __hip_bfloat162 h[4]; } apk;
        apk.h[0] = __float22bfloat162_rn(float2{alo[0], alo[1]});
        apk.h[1] = __float22bfloat162_rn(float2{alo[2], alo[3]});
        apk.h[2] = __float22bfloat162_rn(float2{ahi[0], ahi[1]});
        apk.h[3] = __float22bfloat162_rn(float2{ahi[2], ahi[3]});
        short8 bfv[8];
#pragma unroll
        for (int ft = 0; ft < 8; ++ft)
            bfv[ft] = *reinterpret_cast<const short8*>(A + bo[ft]);

        asm volatile("s_waitcnt lgkmcnt(0)" ::: "memory");
        __builtin_amdgcn_sched_barrier(0);
        __builtin_amdgcn_s_setprio(1);
#pragma unroll
        for (int ft = 0; ft < 8; ++ft)
            acc[ft] = __builtin_amdgcn_mfma_f32_16x16x32_bf16(apk.s, bfv[ft], acc[ft], 0, 0, 0);
        __builtin_amdgcn_s_setprio(0);
        __builtin_amdgcn_sched_barrier(0);

        if (ks < KSTEPS - 2)       asm volatile("s_waitcnt vmcnt(3)" ::: "memory");  // ks+1 landed
        else if (ks == KSTEPS - 2) asm volatile("s_waitcnt vmcnt(0)" ::: "memory");  // tail drain
        if (ks < KSTEPS - 1) {
            __builtin_amdgcn_s_barrier();
            __builtin_amdgcn_sched_barrier(0);
        }
        cur = (cur + 1 == 3) ? 0 : cur + 1;
        stg = (stg + 1 == 3) ? 0 : stg + 1;
    }
#undef STAGE

    // epilogue: C row = n0 + wv*16 + kg*4 + rr, col = ft*16 + lrow
    const int crow = n0 + wv * 16 + (kg << 2);
    float* pb = partial + ((size_t)split * 1024 + crow) * FD + lrow;
#pragma unroll
    for (int ft = 0; ft < 8; ++ft)
#pragma unroll
        for (int rr = 0; rr < 4; ++rr)
            __builtin_nontemporal_store(acc[ft][rr], pb + (size_t)rr * FD + ft * 16);
}

// Stage 4: reduce split-K partials (nt loads: don't evict masks), cosine sim
__global__ __launch_bounds__(128) void k_sims(const float* __restrict__ partial,
                                              const float* __restrict__ rep0,
                                              float* __restrict__ sims)
{
    const int n = blockIdx.x;
    const int f = threadIdx.x;
    float rsum = 0.f;
    for (int s = 0; s < NSPLIT; ++s)
        rsum += __builtin_nontemporal_load(partial + ((size_t)s * 1024 + n) * FD + f);
    const float r0 = rep0[f];
    __shared__ float red0[128], red1[128], red2[128];
    red0[f] = rsum * r0;
    red1[f] = rsum * rsum;
    red2[f] = r0 * r0;
    __syncthreads();
    for (int o = 64; o > 0; o >>= 1) {
        if (f < o) {
            red0[f] += red0[f + o];
            red1[f] += red1[f + o];
            red2[f] += red2[f + o];
        }
        __syncthreads();
    }
    if (f == 0) {
        const float nr = fmaxf(sqrtf(red1[0]), 1e-8f);
        const float nz = fmaxf(sqrtf(red2[0]), 1e-8f);
        sims[n] = red0[0] / (nr * nz);
    }
}

// Stage 5a: per-pixel weighted sums S0,S1,S2 over an n-chunk, float4 pixels
__global__ __launch_bounds__(256) void k_colsums(const float* __restrict__ masks,
                                                 const float* __restrict__ sims,
                                                 float* __restrict__ Spart)
{
    __shared__ float s1v[NPB], s2v[NPB];
    const int t = threadIdx.x;
    const int split = blockIdx.y;
    if (t < NPB) {
        const float s = sims[split * NPB + t];
        s1v[t] = s;
        s2v[t] = s * s;
    }
    __syncthreads();
    const int pix = (blockIdx.x * 256 + t) * 4;
    const float* mp = masks + (size_t)split * NPB * HWN + pix;
    f32x4 s0 = {0.f,0.f,0.f,0.f}, s1 = s0, s2 = s0;
#pragma unroll 5
    for (int i = 0; i < NPB; ++i) {
        const f32x4 m = *reinterpret_cast<const f32x4*>(mp + (size_t)i * HWN);
        const float a = s1v[i], b = s2v[i];
        s0 += m;
#pragma unroll
        for (int e = 0; e < 4; ++e) {
            s1[e] = fmaf(m[e], a, s1[e]);
            s2[e] = fmaf(m[e], b, s2[e]);
        }
    }
    float* sp = Spart + (size_t)split * 3 * HWN + pix;
    __builtin_nontemporal_store(s0, reinterpret_cast<f32x4*>(sp));
    __builtin_nontemporal_store(s1, reinterpret_cast<f32x4*>(sp + HWN));
    __builtin_nontemporal_store(s2, reinterpret_cast<f32x4*>(sp + 2 * HWN));
}

// Stage 5b: combine splits, closed-form imp/unc/sow
__global__ __launch_bounds__(256) void k_final(const float* __restrict__ Spart,
                                               float* __restrict__ out)
{
    const int pix = (blockIdx.x * 256 + threadIdx.x) * 4;
    f32x4 s0 = {0.f,0.f,0.f,0.f}, s1 = s0, s2 = s0;
#pragma unroll 4
    for (int sp = 0; sp < NSCAN; ++sp) {
        const float* p = Spart + (size_t)sp * 3 * HWN + pix;
        s0 += __builtin_nontemporal_load(reinterpret_cast<const f32x4*>(p));
        s1 += __builtin_nontemporal_load(reinterpret_cast<const f32x4*>(p + HWN));
        s2 += __builtin_nontemporal_load(reinterpret_cast<const f32x4*>(p + 2 * HWN));
    }
    f32x4 imp, unc, sow;
#pragma unroll
    for (int e = 0; e < 4; ++e) {
        sow[e] = 1e-10f + s0[e];
        imp[e] = s1[e] / sow[e];
        unc[e] = fmaf(-imp[e], s1[e], s2[e]);   // S2 - S1^2/sow
    }
    *reinterpret_cast<f32x4*>(out + pix) = imp;
    *reinterpret_cast<f32x4*>(out + HWN + pix) = unc;
    *reinterpret_cast<f32x4*>(out + 2 * HWN + pix) = sow;
}

extern "C" void kernel_launch(void* const* d_in, const int* in_sizes, int n_in,
                              void* d_out, int out_size, void* d_ws, size_t ws_size,
                              hipStream_t stream) {
    const float* img   = (const float*)d_in[0];
    const float* masks = (const float*)d_in[1];
    const float* Wt    = (const float*)d_in[2];
    float* out = (float*)d_out;

    char* ws = (char*)d_ws;
    unsigned short* Bpack = (unsigned short*)ws;                 // 12,845,056 B
    float* partial  = (float*)(ws + 12845056);                   // 98*1024*128*4 = 51,380,224 B
    float* rep0part = partial;                                   // alias: consumed before gemm writes
    float* rep0     = (float*)(ws + 64225280);                   // 512 B
    float* sims     = (float*)(ws + 64225792);                   // 4,000 B
    float* Spart    = (float*)ws;                                // alias Bpack (12,042,240 B)

    hipLaunchKernelGGL(k_encode,  dim3(784), dim3(256), 0, stream, img, Wt, Bpack, rep0part);
    hipLaunchKernelGGL(k_rep0red, dim3(128), dim3(256), 0, stream, rep0part, rep0);
    hipLaunchKernelGGL(k_gemm,    dim3(8, NSPLIT), dim3(512), 0, stream, masks, Bpack, partial);
    hipLaunchKernelGGL(k_sims,    dim3(NM), dim3(128), 0, stream, partial, rep0, sims);
    hipLaunchKernelGGL(k_colsums, dim3(49, NSCAN), dim3(256), 0, stream, masks, sims, Spart);
    hipLaunchKernelGGL(k_final,   dim3(49), dim3(256), 0, stream, Spart, out);
}

// Round 6
// 136.573 us; speedup vs baseline: 1.0334x; 1.0334x over previous
//
#include <hip/hip_runtime.h>
#include <hip/hip_bf16.h>
#include <stdint.h>

#define HWN 50176   // 224*224
#define NM  1000
#define FD  128
#define NSPLIT 98   // 512-wide k-chunks
#define KSTEPS 16
#define NSCAN 20
#define NPB 50      // 1000 / 20

typedef __attribute__((ext_vector_type(8))) short short8;
typedef __attribute__((ext_vector_type(4))) float f32x4;

__device__ __forceinline__ unsigned short f2bf(float x) {
    union { float f; unsigned u; } v; v.f = x;
    unsigned r = v.u + 0x7FFFu + ((v.u >> 16) & 1u);
    return (unsigned short)(r >> 16);
}

#define AS1(p) ((const __attribute__((address_space(1))) unsigned int*)(p))
#define AS3(p) ((__attribute__((address_space(3))) unsigned int*)(p))

// Stage 1: A[hw,f] = sum_c img*W, packed bf16 k-tiles (B operand of the GEMM).
// Tile kt (8192B): 16B chunk (f, kg) [kg = k-subchunk of 8] stored at slot
// (f*4+kg) ^ ((f>>1)&3)  -> ds_read_b128 B-fragment reads are <=2-way (free).
__global__ __launch_bounds__(256) void k_encode(const float* __restrict__ img,
                                                const float* __restrict__ Wt,
                                                unsigned short* __restrict__ Bpack,
                                                float* __restrict__ rep0part)
{
    const int t = threadIdx.x;
    const int f = t & 127;
    const int kt = blockIdx.x * 2 + (t >> 7);
    const int hw0 = kt * 32;
    float vals[32];
    float rsum = 0.f;
#pragma unroll
    for (int e = 0; e < 32; ++e) {
        const int hw = hw0 + e;
        float a = img[hw] * Wt[(size_t)hw * FD + f];
        a = fmaf(img[HWN + hw],     Wt[(size_t)(HWN + hw) * FD + f], a);
        a = fmaf(img[2 * HWN + hw], Wt[(size_t)(2 * HWN + hw) * FD + f], a);
        vals[e] = a;
        rsum += a;
    }
    char* tile = (char*)Bpack + (size_t)kt * 8192;
#pragma unroll
    for (int j = 0; j < 4; ++j) {
        short8 pk;
#pragma unroll
        for (int e = 0; e < 8; ++e) pk[e] = (short)f2bf(vals[j * 8 + e]);
        const int slot = (f * 4 + j) ^ ((f >> 1) & 3);
        *reinterpret_cast<short8*>(tile + (slot << 4)) = pk;
    }
    __shared__ float red[256];
    red[t] = rsum;
    __syncthreads();
    if (t < 128) rep0part[(size_t)blockIdx.x * 128 + f] = red[t] + red[t + 128];
}

// Stage 2: rep0[f] = sum of 784 partials
__global__ __launch_bounds__(256) void k_rep0red(const float* __restrict__ rep0part,
                                                 float* __restrict__ rep0)
{
    const int f = blockIdx.x;
    float s = 0.f;
    for (int b = threadIdx.x; b < 784; b += 256) s += rep0part[(size_t)b * 128 + f];
    __shared__ float red[256];
    red[threadIdx.x] = s;
    __syncthreads();
    for (int o = 128; o > 0; o >>= 1) {
        if (threadIdx.x < o) red[threadIdx.x] += red[threadIdx.x + o];
        __syncthreads();
    }
    if (threadIdx.x == 0) rep0[f] = red[0];
}

// Stage 3: split-K GEMM. 128-row tile, 4 waves x 32 rows, grid 784 (8 stripes
// x 98 splits, XCD-bijective swizzle). Counted vmcnt(6) double-buffer; B-frags
// register-cached across the wave's 2 row-groups; conflict-free LDS swizzles.
__global__ __launch_bounds__(256, 3) void k_gemm(const float* __restrict__ masks,
                                                 const unsigned short* __restrict__ Bpack,
                                                 float* __restrict__ partial)
{
    __shared__ __align__(16) char lds[2][24576];   // A fp32 16KB | B bf16 8KB

    const int t = threadIdx.x;
    const int wv = t >> 6, lane = t & 63;
    const int lrow = lane & 15, kg = lane >> 4;

    // XCD-bijective swizzle: each XCD gets a contiguous range of splits, and
    // all 8 stripes of a split land on the same XCD (B-pack L2-resident,
    // masks partitioned 1/8 per XCD).
    const int bid = blockIdx.x;
    const int swz = (bid & 7) * 98 + (bid >> 3);
    const int split = swz >> 3, mtile = swz & 7;
    const int n0 = mtile * 128;

    // ---- A staging: 128 rows x 32 k fp32 = 16KB, 4 gll ops. LDS slot
    // s = o*256+t holds row (s>>3), chunk c = (s&7)^(row&7) (inverse-swizzled
    // source, linear dest).
    const int arow_l = t >> 3;                         // local row % 32 per op
    const int cA = (t & 7) ^ (arow_l & 7);
    const float* aSrc[4];
#pragma unroll
    for (int o = 0; o < 4; ++o) {
        int rowg = n0 + o * 32 + arow_l;
        if (rowg >= NM) rowg = NM - 1;                 // dup rows never read back
        aSrc[o] = masks + (size_t)rowg * HWN + split * 512 + cA * 4;
    }
    const char* bSrc = (const char*)Bpack + (size_t)split * (KSTEPS * 8192) + t * 16;

    // ---- fragment read offsets (loop-invariant)
    int ao[2][2];
#pragma unroll
    for (int g = 0; g < 2; ++g) {
        const int r = wv * 32 + g * 16 + lrow;
#pragma unroll
        for (int w = 0; w < 2; ++w)
            ao[g][w] = r * 128 + (((2 * kg + w) ^ (r & 7)) << 4);
    }
    int bo[8];
#pragma unroll
    for (int ft = 0; ft < 8; ++ft) {
        const int f = ft * 16 + lrow;
        bo[ft] = 16384 + (((f * 4 + kg) ^ ((f >> 1) & 3)) << 4);
    }

    f32x4 acc[2][8];
#pragma unroll
    for (int g = 0; g < 2; ++g)
#pragma unroll
        for (int i = 0; i < 8; ++i) acc[g][i] = f32x4{0.f, 0.f, 0.f, 0.f};

#define STAGE(KS, BUF) do {                                                                   \
        char* b_ = &lds[BUF][0];                                                              \
        __builtin_amdgcn_global_load_lds(AS1(aSrc[0] + (KS) * 32), AS3(b_ + t * 16), 16, 0, 0);          \
        __builtin_amdgcn_global_load_lds(AS1(aSrc[1] + (KS) * 32), AS3(b_ + 4096  + t * 16), 16, 0, 0);  \
        __builtin_amdgcn_global_load_lds(AS1(aSrc[2] + (KS) * 32), AS3(b_ + 8192  + t * 16), 16, 0, 0);  \
        __builtin_amdgcn_global_load_lds(AS1(aSrc[3] + (KS) * 32), AS3(b_ + 12288 + t * 16), 16, 0, 0);  \
        __builtin_amdgcn_global_load_lds(AS1(bSrc + (size_t)(KS) * 8192),        AS3(b_ + 16384 + t * 16), 16, 0, 0); \
        __builtin_amdgcn_global_load_lds(AS1(bSrc + (size_t)(KS) * 8192 + 4096), AS3(b_ + 20480 + t * 16), 16, 0, 0); \
    } while (0)

    STAGE(0, 0);

    for (int ks = 0; ks < KSTEPS; ++ks) {
        const int cur = ks & 1;
        if (ks + 1 < KSTEPS) STAGE(ks + 1, cur ^ 1);
        if (ks + 1 < KSTEPS) asm volatile("s_waitcnt vmcnt(6)" ::: "memory");  // step ks landed
        else                 asm volatile("s_waitcnt vmcnt(0)" ::: "memory");
        __builtin_amdgcn_s_barrier();          // all waves' staging of buf[cur] complete
        __builtin_amdgcn_sched_barrier(0);

        const char* B = &lds[cur][0];
        // B fragments: read ONCE, reused for both row groups
        short8 bfv[8];
#pragma unroll
        for (int ft = 0; ft < 8; ++ft)
            bfv[ft] = *reinterpret_cast<const short8*>(B + bo[ft]);
        // A fragments for the 2 row groups
        f32x4 alo0 = *reinterpret_cast<const f32x4*>(B + ao[0][0]);
        f32x4 ahi0 = *reinterpret_cast<const f32x4*>(B + ao[0][1]);
        f32x4 alo1 = *reinterpret_cast<const f32x4*>(B + ao[1][0]);
        f32x4 ahi1 = *reinterpret_cast<const f32x4*>(B + ao[1][1]);

        union { short8 s; __hip_bfloat162 h[4]; } apk0, apk1;
        apk0.h[0] = __float22bfloat162_rn(float2{alo0[0], alo0[1]});
        apk0.h[1] = __float22bfloat162_rn(float2{alo0[2], alo0[3]});
        apk0.h[2] = __float22bfloat162_rn(float2{ahi0[0], ahi0[1]});
        apk0.h[3] = __float22bfloat162_rn(float2{ahi0[2], ahi0[3]});
        apk1.h[0] = __float22bfloat162_rn(float2{alo1[0], alo1[1]});
        apk1.h[1] = __float22bfloat162_rn(float2{alo1[2], alo1[3]});
        apk1.h[2] = __float22bfloat162_rn(float2{ahi1[0], ahi1[1]});
        apk1.h[3] = __float22bfloat162_rn(float2{ahi1[2], ahi1[3]});

        asm volatile("s_waitcnt lgkmcnt(0)" ::: "memory");
        __builtin_amdgcn_sched_barrier(0);
        __builtin_amdgcn_s_setprio(1);
#pragma unroll
        for (int ft = 0; ft < 8; ++ft)
            acc[0][ft] = __builtin_amdgcn_mfma_f32_16x16x32_bf16(apk0.s, bfv[ft], acc[0][ft], 0, 0, 0);
#pragma unroll
        for (int ft = 0; ft < 8; ++ft)
            acc[1][ft] = __builtin_amdgcn_mfma_f32_16x16x32_bf16(apk1.s, bfv[ft], acc[1][ft], 0, 0, 0);
        __builtin_amdgcn_s_setprio(0);
        __builtin_amdgcn_sched_barrier(0);
        __builtin_amdgcn_s_barrier();          // frag reads done before next STAGE overwrites
        __builtin_amdgcn_sched_barrier(0);
    }
#undef STAGE

    // epilogue: C row = n0 + wv*32 + g*16 + kg*4 + rr, col = ft*16 + lrow
#pragma unroll
    for (int g = 0; g < 2; ++g) {
        const int crow = n0 + wv * 32 + g * 16 + (kg << 2);
        float* pb = partial + ((size_t)split * 1024 + crow) * FD + lrow;
#pragma unroll
        for (int ft = 0; ft < 8; ++ft)
#pragma unroll
            for (int rr = 0; rr < 4; ++rr)
                __builtin_nontemporal_store(acc[g][ft][rr], pb + (size_t)rr * FD + ft * 16);
    }
}

// Stage 4: reduce split-K partials (nt loads: don't evict masks), cosine sim
__global__ __launch_bounds__(128) void k_sims(const float* __restrict__ partial,
                                              const float* __restrict__ rep0,
                                              float* __restrict__ sims)
{
    const int n = blockIdx.x;
    const int f = threadIdx.x;
    float rsum = 0.f;
    for (int s = 0; s < NSPLIT; ++s)
        rsum += __builtin_nontemporal_load(partial + ((size_t)s * 1024 + n) * FD + f);
    const float r0 = rep0[f];
    __shared__ float red0[128], red1[128], red2[128];
    red0[f] = rsum * r0;
    red1[f] = rsum * rsum;
    red2[f] = r0 * r0;
    __syncthreads();
    for (int o = 64; o > 0; o >>= 1) {
        if (f < o) {
            red0[f] += red0[f + o];
            red1[f] += red1[f + o];
            red2[f] += red2[f + o];
        }
        __syncthreads();
    }
    if (f == 0) {
        const float nr = fmaxf(sqrtf(red1[0]), 1e-8f);
        const float nz = fmaxf(sqrtf(red2[0]), 1e-8f);
        sims[n] = red0[0] / (nr * nz);
    }
}

// Stage 5a: per-pixel weighted sums S0,S1,S2 over an n-chunk, float4 pixels
__global__ __launch_bounds__(256) void k_colsums(const float* __restrict__ masks,
                                                 const float* __restrict__ sims,
                                                 float* __restrict__ Spart)
{
    __shared__ float s1v[NPB], s2v[NPB];
    const int t = threadIdx.x;
    const int split = blockIdx.y;
    if (t < NPB) {
        const float s = sims[split * NPB + t];
        s1v[t] = s;
        s2v[t] = s * s;
    }
    __syncthreads();
    const int pix = (blockIdx.x * 256 + t) * 4;
    const float* mp = masks + (size_t)split * NPB * HWN + pix;
    f32x4 s0 = {0.f,0.f,0.f,0.f}, s1 = s0, s2 = s0;
#pragma unroll 5
    for (int i = 0; i < NPB; ++i) {
        const f32x4 m = *reinterpret_cast<const f32x4*>(mp + (size_t)i * HWN);
        const float a = s1v[i], b = s2v[i];
        s0 += m;
#pragma unroll
        for (int e = 0; e < 4; ++e) {
            s1[e] = fmaf(m[e], a, s1[e]);
            s2[e] = fmaf(m[e], b, s2[e]);
        }
    }
    float* sp = Spart + (size_t)split * 3 * HWN + pix;
    __builtin_nontemporal_store(s0, reinterpret_cast<f32x4*>(sp));
    __builtin_nontemporal_store(s1, reinterpret_cast<f32x4*>(sp + HWN));
    __builtin_nontemporal_store(s2, reinterpret_cast<f32x4*>(sp + 2 * HWN));
}

// Stage 5b: combine splits, closed-form imp/unc/sow
__global__ __launch_bounds__(256) void k_final(const float* __restrict__ Spart,
                                               float* __restrict__ out)
{
    const int pix = (blockIdx.x * 256 + threadIdx.x) * 4;
    f32x4 s0 = {0.f,0.f,0.f,0.f}, s1 = s0, s2 = s0;
#pragma unroll 4
    for (int sp = 0; sp < NSCAN; ++sp) {
        const float* p = Spart + (size_t)sp * 3 * HWN + pix;
        s0 += __builtin_nontemporal_load(reinterpret_cast<const f32x4*>(p));
        s1 += __builtin_nontemporal_load(reinterpret_cast<const f32x4*>(p + HWN));
        s2 += __builtin_nontemporal_load(reinterpret_cast<const f32x4*>(p + 2 * HWN));
    }
    f32x4 imp, unc, sow;
#pragma unroll
    for (int e = 0; e < 4; ++e) {
        sow[e] = 1e-10f + s0[e];
        imp[e] = s1[e] / sow[e];
        unc[e] = fmaf(-imp[e], s1[e], s2[e]);   // S2 - S1^2/sow
    }
    *reinterpret_cast<f32x4*>(out + pix) = imp;
    *reinterpret_cast<f32x4*>(out + HWN + pix) = unc;
    *reinterpret_cast<f32x4*>(out + 2 * HWN + pix) = sow;
}

extern "C" void kernel_launch(void* const* d_in, const int* in_sizes, int n_in,
                              void* d_out, int out_size, void* d_ws, size_t ws_size,
                              hipStream_t stream) {
    const float* img   = (const float*)d_in[0];
    const float* masks = (const float*)d_in[1];
    const float* Wt    = (const float*)d_in[2];
    float* out = (float*)d_out;

    char* ws = (char*)d_ws;
    unsigned short* Bpack = (unsigned short*)ws;                 // 12,845,056 B
    float* partial  = (float*)(ws + 12845056);                   // 98*1024*128*4 = 51,380,224 B
    float* rep0part = partial;                                   // alias: consumed before gemm writes
    float* rep0     = (float*)(ws + 64225280);                   // 512 B
    float* sims     = (float*)(ws + 64225792);                   // 4,000 B
    float* Spart    = (float*)ws;                                // alias Bpack (12,042,240 B)

    hipLaunchKernelGGL(k_encode,  dim3(784), dim3(256), 0, stream, img, Wt, Bpack, rep0part);
    hipLaunchKernelGGL(k_rep0red, dim3(128), dim3(256), 0, stream, rep0part, rep0);
    hipLaunchKernelGGL(k_gemm,    dim3(784), dim3(256), 0, stream, masks, Bpack, partial);
    hipLaunchKernelGGL(k_sims,    dim3(NM), dim3(128), 0, stream, partial, rep0, sims);
    hipLaunchKernelGGL(k_colsums, dim3(49, NSCAN), dim3(256), 0, stream, masks, sims, Spart);
    hipLaunchKernelGGL(k_final,   dim3(49), dim3(256), 0, stream, Spart, out);
}

// Round 7
// 123.343 us; speedup vs baseline: 1.1443x; 1.1073x over previous
//
#include <hip/hip_runtime.h>
#include <hip/hip_bf16.h>
#include <stdint.h>

#define HWN 50176   // 224*224
#define NM  1000
#define FD  128
#define NSPLIT 49   // 1024-wide k-chunks
#define KSTEPS 32
#define NSCAN 20
#define NPB 50      // 1000 / 20

typedef __attribute__((ext_vector_type(8))) short short8;
typedef __attribute__((ext_vector_type(4))) float f32x4;

__device__ __forceinline__ unsigned short f2bf(float x) {
    union { float f; unsigned u; } v; v.f = x;
    unsigned r = v.u + 0x7FFFu + ((v.u >> 16) & 1u);
    return (unsigned short)(r >> 16);
}

#define AS1(p) ((const __attribute__((address_space(1))) unsigned int*)(p))
#define AS3(p) ((__attribute__((address_space(3))) unsigned int*)(p))

// Stage 1: A[hw,f] = sum_c img*W, packed bf16 k-tiles (GEMM B operand).
// Tile kt (8192B): 16B chunk (f, j) at slot (f*4+j)^((f>>1)&3).
// W read nontemporal: streamed once, keep masks L3-resident.
__global__ __launch_bounds__(256) void k_encode(const float* __restrict__ img,
                                                const float* __restrict__ Wt,
                                                unsigned short* __restrict__ Bpack,
                                                float* __restrict__ rep0part)
{
    const int t = threadIdx.x;
    const int f = t & 127;
    const int kt = blockIdx.x * 2 + (t >> 7);
    const int hw0 = kt * 32;
    float vals[32];
    float rsum = 0.f;
#pragma unroll
    for (int e = 0; e < 32; ++e) {
        const int hw = hw0 + e;
        float a = img[hw] * __builtin_nontemporal_load(Wt + (size_t)hw * FD + f);
        a = fmaf(img[HWN + hw],     __builtin_nontemporal_load(Wt + (size_t)(HWN + hw) * FD + f), a);
        a = fmaf(img[2 * HWN + hw], __builtin_nontemporal_load(Wt + (size_t)(2 * HWN + hw) * FD + f), a);
        vals[e] = a;
        rsum += a;
    }
    char* tile = (char*)Bpack + (size_t)kt * 8192;
#pragma unroll
    for (int j = 0; j < 4; ++j) {
        short8 pk;
#pragma unroll
        for (int e = 0; e < 8; ++e) pk[e] = (short)f2bf(vals[j * 8 + e]);
        const int slot = (f * 4 + j) ^ ((f >> 1) & 3);
        *reinterpret_cast<short8*>(tile + (slot << 4)) = pk;
    }
    __shared__ float red[256];
    red[t] = rsum;
    __syncthreads();
    if (t < 128) rep0part[(size_t)blockIdx.x * 128 + f] = red[t] + red[t + 128];
}

// Stage 2: rep0[f] = sum of 784 partials
__global__ __launch_bounds__(256) void k_rep0red(const float* __restrict__ rep0part,
                                                 float* __restrict__ rep0)
{
    const int f = blockIdx.x;
    float s = 0.f;
    for (int b = threadIdx.x; b < 784; b += 256) s += rep0part[(size_t)b * 128 + f];
    __shared__ float red[256];
    red[threadIdx.x] = s;
    __syncthreads();
    for (int o = 128; o > 0; o >>= 1) {
        if (threadIdx.x < o) red[threadIdx.x] += red[threadIdx.x + o];
        __syncthreads();
    }
    if (threadIdx.x == 0) rep0[f] = red[0];
}

// Stage 3: split-K GEMM. 64-row tile, 4 waves/256 thr, grid 16x49=784.
// A (masks) in REGISTERS, depth-2 prefetch. B via global_load_lds, 3 buffers.
// Exact counted vmcnt: 4 vmem ops/step (2 B-gll + 2 A-loads) inside fences;
// steady-state wait vmcnt(8); never drains inside the loop.
__global__ __launch_bounds__(256, 4) void k_gemm(const float* __restrict__ masks,
                                                 const unsigned short* __restrict__ Bpack,
                                                 float* __restrict__ partial)
{
    __shared__ __align__(16) char Bs[3][8192];

    const int t = threadIdx.x;
    const int wv = t >> 6, lane = t & 63;
    const int lrow = lane & 15, kg = lane >> 4;

    // XCD-bijective swizzle (784 = 8*98): XCD x gets contiguous swz range.
    const int bid = blockIdx.x;
    const int swz = (bid & 7) * 98 + (bid >> 3);
    const int split = swz >> 4, mtile = swz & 15;
    const int n0 = mtile * 64;

    int row = n0 + wv * 16 + lrow;
    if (row >= NM) row = NM - 1;                  // dup rows never read back
    const float* aSrc = masks + (size_t)row * HWN + split * 1024 + kg * 8;
    const char*  bSrc = (const char*)Bpack + (size_t)split * (KSTEPS * 8192) + t * 16;

    int bo[8];
#pragma unroll
    for (int ft = 0; ft < 8; ++ft) {
        const int f = ft * 16 + lrow;
        bo[ft] = ((f * 4 + kg) ^ ((f >> 1) & 3)) << 4;
    }

    f32x4 acc[8];
#pragma unroll
    for (int i = 0; i < 8; ++i) acc[i] = f32x4{0.f, 0.f, 0.f, 0.f};

    // Named rotating A-register buffers (static indexing only — rule #20).
    f32x4 aA0, aA1, aB0, aB1, aC0, aC1;

#define STAGE(KS, BUFOFF) do {                                                                     \
        __builtin_amdgcn_global_load_lds(AS1(bSrc + (size_t)(KS) * 8192),        AS3(&Bs[0][0] + (BUFOFF) + ((t & 255) * 16)), 16, 0, 0); \
        __builtin_amdgcn_global_load_lds(AS1(bSrc + (size_t)(KS) * 8192 + 4096), AS3(&Bs[0][0] + (BUFOFF) + 4096 + ((t & 255) * 16)), 16, 0, 0); \
    } while (0)
    // NOTE: both gll lines stage 4KB each (256 thr x 16B); second covers +4096.

    // prologue: steps 0,1 in flight (8 vmem ops)
    __builtin_amdgcn_sched_barrier(0);
    STAGE(0, 0);
    aA0 = *reinterpret_cast<const f32x4*>(aSrc);
    aA1 = *reinterpret_cast<const f32x4*>(aSrc + 4);
    __builtin_amdgcn_sched_barrier(0);
    STAGE(1, 8192);
    aB0 = *reinterpret_cast<const f32x4*>(aSrc + 32);
    aB1 = *reinterpret_cast<const f32x4*>(aSrc + 36);
    __builtin_amdgcn_sched_barrier(0);

    int boff_c = 0;          // buffer offset of step ks
    for (int ks = 0; ks < KSTEPS; ++ks) {
        const int boff_s = (boff_c + 16384 >= 24576) ? (boff_c + 16384 - 24576) : (boff_c + 16384);
        if (ks + 2 < KSTEPS) {
            __builtin_amdgcn_sched_barrier(0);
            STAGE(ks + 2, boff_s);
            aC0 = *reinterpret_cast<const f32x4*>(aSrc + (ks + 2) * 32);
            aC1 = *reinterpret_cast<const f32x4*>(aSrc + (ks + 2) * 32 + 4);
            __builtin_amdgcn_sched_barrier(0);
            asm volatile("s_waitcnt vmcnt(8)" ::: "memory");   // step ks fully landed
        } else if (ks == KSTEPS - 2) {
            asm volatile("s_waitcnt vmcnt(4)" ::: "memory");
        } else {
            asm volatile("s_waitcnt vmcnt(0)" ::: "memory");
        }
        __builtin_amdgcn_s_barrier();            // buf[ks] visible to all waves
        __builtin_amdgcn_sched_barrier(0);

        const char* B = &Bs[0][0] + boff_c;
        short8 bfv[8];
#pragma unroll
        for (int ft = 0; ft < 8; ++ft)
            bfv[ft] = *reinterpret_cast<const short8*>(B + bo[ft]);

        union { short8 s; __hip_bfloat162 h[4]; } apk;
        apk.h[0] = __float22bfloat162_rn(float2{aA0[0], aA0[1]});
        apk.h[1] = __float22bfloat162_rn(float2{aA0[2], aA0[3]});
        apk.h[2] = __float22bfloat162_rn(float2{aA1[0], aA1[1]});
        apk.h[3] = __float22bfloat162_rn(float2{aA1[2], aA1[3]});

        asm volatile("s_waitcnt lgkmcnt(0)" ::: "memory");
        __builtin_amdgcn_sched_barrier(0);
        __builtin_amdgcn_s_setprio(1);
#pragma unroll
        for (int ft = 0; ft < 8; ++ft)
            acc[ft] = __builtin_amdgcn_mfma_f32_16x16x32_bf16(apk.s, bfv[ft], acc[ft], 0, 0, 0);
        __builtin_amdgcn_s_setprio(0);
        __builtin_amdgcn_sched_barrier(0);
        if (ks + 1 < KSTEPS) {
            __builtin_amdgcn_s_barrier();        // frag reads done before staging over buf
            __builtin_amdgcn_sched_barrier(0);
        }
        // rotate A-regs and buffer offset
        aA0 = aB0; aA1 = aB1; aB0 = aC0; aB1 = aC1;
        boff_c = (boff_c + 8192 >= 24576) ? 0 : (boff_c + 8192);
    }
#undef STAGE

    // epilogue: C row = n0 + wv*16 + kg*4 + rr, col = ft*16 + lrow
    const int crow = n0 + wv * 16 + (kg << 2);
    float* pb = partial + ((size_t)split * 1024 + crow) * FD + lrow;
#pragma unroll
    for (int ft = 0; ft < 8; ++ft)
#pragma unroll
        for (int rr = 0; rr < 4; ++rr)
            __builtin_nontemporal_store(acc[ft][rr], pb + (size_t)rr * FD + ft * 16);
}

// Stage 4: reduce split-K partials (nt loads), cosine sim
__global__ __launch_bounds__(128) void k_sims(const float* __restrict__ partial,
                                              const float* __restrict__ rep0,
                                              float* __restrict__ sims)
{
    const int n = blockIdx.x;
    const int f = threadIdx.x;
    float rsum = 0.f;
    for (int s = 0; s < NSPLIT; ++s)
        rsum += __builtin_nontemporal_load(partial + ((size_t)s * 1024 + n) * FD + f);
    const float r0 = rep0[f];
    __shared__ float red0[128], red1[128], red2[128];
    red0[f] = rsum * r0;
    red1[f] = rsum * rsum;
    red2[f] = r0 * r0;
    __syncthreads();
    for (int o = 64; o > 0; o >>= 1) {
        if (f < o) {
            red0[f] += red0[f + o];
            red1[f] += red1[f + o];
            red2[f] += red2[f + o];
        }
        __syncthreads();
    }
    if (f == 0) {
        const float nr = fmaxf(sqrtf(red1[0]), 1e-8f);
        const float nz = fmaxf(sqrtf(red2[0]), 1e-8f);
        sims[n] = red0[0] / (nr * nz);
    }
}

// Stage 5a: per-pixel weighted sums S0,S1,S2 over an n-chunk, float4 pixels
__global__ __launch_bounds__(256) void k_colsums(const float* __restrict__ masks,
                                                 const float* __restrict__ sims,
                                                 float* __restrict__ Spart)
{
    __shared__ float s1v[NPB], s2v[NPB];
    const int t = threadIdx.x;
    const int split = blockIdx.y;
    if (t < NPB) {
        const float s = sims[split * NPB + t];
        s1v[t] = s;
        s2v[t] = s * s;
    }
    __syncthreads();
    const int pix = (blockIdx.x * 256 + t) * 4;
    const float* mp = masks + (size_t)split * NPB * HWN + pix;
    f32x4 s0 = {0.f,0.f,0.f,0.f}, s1 = s0, s2 = s0;
#pragma unroll 5
    for (int i = 0; i < NPB; ++i) {
        const f32x4 m = *reinterpret_cast<const f32x4*>(mp + (size_t)i * HWN);
        const float a = s1v[i], b = s2v[i];
        s0 += m;
#pragma unroll
        for (int e = 0; e < 4; ++e) {
            s1[e] = fmaf(m[e], a, s1[e]);
            s2[e] = fmaf(m[e], b, s2[e]);
        }
    }
    float* sp = Spart + (size_t)split * 3 * HWN + pix;
    __builtin_nontemporal_store(s0, reinterpret_cast<f32x4*>(sp));
    __builtin_nontemporal_store(s1, reinterpret_cast<f32x4*>(sp + HWN));
    __builtin_nontemporal_store(s2, reinterpret_cast<f32x4*>(sp + 2 * HWN));
}

// Stage 5b: combine splits, closed-form imp/unc/sow
__global__ __launch_bounds__(256) void k_final(const float* __restrict__ Spart,
                                               float* __restrict__ out)
{
    const int pix = (blockIdx.x * 256 + threadIdx.x) * 4;
    f32x4 s0 = {0.f,0.f,0.f,0.f}, s1 = s0, s2 = s0;
#pragma unroll 4
    for (int sp = 0; sp < NSCAN; ++sp) {
        const float* p = Spart + (size_t)sp * 3 * HWN + pix;
        s0 += __builtin_nontemporal_load(reinterpret_cast<const f32x4*>(p));
        s1 += __builtin_nontemporal_load(reinterpret_cast<const f32x4*>(p + HWN));
        s2 += __builtin_nontemporal_load(reinterpret_cast<const f32x4*>(p + 2 * HWN));
    }
    f32x4 imp, unc, sow;
#pragma unroll
    for (int e = 0; e < 4; ++e) {
        sow[e] = 1e-10f + s0[e];
        imp[e] = s1[e] / sow[e];
        unc[e] = fmaf(-imp[e], s1[e], s2[e]);   // S2 - S1^2/sow
    }
    *reinterpret_cast<f32x4*>(out + pix) = imp;
    *reinterpret_cast<f32x4*>(out + HWN + pix) = unc;
    *reinterpret_cast<f32x4*>(out + 2 * HWN + pix) = sow;
}

extern "C" void kernel_launch(void* const* d_in, const int* in_sizes, int n_in,
                              void* d_out, int out_size, void* d_ws, size_t ws_size,
                              hipStream_t stream) {
    const float* img   = (const float*)d_in[0];
    const float* masks = (const float*)d_in[1];
    const float* Wt    = (const float*)d_in[2];
    float* out = (float*)d_out;

    char* ws = (char*)d_ws;
    unsigned short* Bpack = (unsigned short*)ws;                 // 12,845,056 B
    float* partial  = (float*)(ws + 12845056);                   // 49*1024*128*4 = 25,690,112 B
    float* rep0part = partial;                                   // alias: consumed before gemm writes
    float* rep0     = (float*)(ws + 38535168);                   // 512 B
    float* sims     = (float*)(ws + 38535680);                   // 4,000 B
    float* Spart    = (float*)ws;                                // alias Bpack (12,042,240 B)

    hipLaunchKernelGGL(k_encode,  dim3(784), dim3(256), 0, stream, img, Wt, Bpack, rep0part);
    hipLaunchKernelGGL(k_rep0red, dim3(128), dim3(256), 0, stream, rep0part, rep0);
    hipLaunchKernelGGL(k_gemm,    dim3(784), dim3(256), 0, stream, masks, Bpack, partial);
    hipLaunchKernelGGL(k_sims,    dim3(NM), dim3(128), 0, stream, partial, rep0, sims);
    hipLaunchKernelGGL(k_colsums, dim3(49, NSCAN), dim3(256), 0, stream, masks, sims, Spart);
    hipLaunchKernelGGL(k_final,   dim3(49), dim3(256), 0, stream, Spart, out);
}